// Round 4
// baseline (15211.542 us; speedup 1.0000x reference)
//
#include <hip/hip_runtime.h>
#include <math.h>

#define NBLOCKS 256
#define NTHREADS 512
#define WPB 8                 // waves per block
#define HDIM 4096
#define NPAIR (HDIM/2)        // 2048 f16x2 pairs

typedef _Float16 f16x2  __attribute__((ext_vector_type(2)));
typedef _Float16 f16x16 __attribute__((ext_vector_type(16)));
typedef unsigned long long u64;

union UF { unsigned u; f16x2 h; };

__device__ __forceinline__ float dot2f(f16x2 a, f16x2 b, float c) {
  return __builtin_amdgcn_fdot2(a, b, c, false);   // v_dot2_f32_f16
}
__device__ __forceinline__ float sigmoidf_(float x) {
  return 1.0f / (1.0f + __expf(-x));
}
__device__ __forceinline__ float tanhf_(float x) {
  float a = fabsf(x);
  float t = __expf(-2.0f * a);
  float r = (1.0f - t) / (1.0f + t);
  return copysignf(r, x);
}
__device__ __forceinline__ void st64(u64* p, u64 v) {
  __hip_atomic_store(p, v, __ATOMIC_RELAXED, __HIP_MEMORY_SCOPE_AGENT);
}
__device__ __forceinline__ u64 ld64(const u64* p) {
  return __hip_atomic_load(p, __ATOMIC_RELAXED, __HIP_MEMORY_SCOPE_AGENT);
}

// ---- load one f16x16 chunk (8 f16x2 pairs, pair j at (const float2*)SRC + lane + 64*j) ----
#define LOAD_CHUNK(VAR, SRC, C) do {                                          \
  const float2* s_ = (const float2*)(SRC) + lane + 64 * ((C) * 8);            \
  float2 p0_ = s_[0];   float2 p1_ = s_[64];  float2 p2_ = s_[128];           \
  float2 p3_ = s_[192]; float2 p4_ = s_[256]; float2 p5_ = s_[320];           \
  float2 p6_ = s_[384]; float2 p7_ = s_[448];                                 \
  VAR = (f16x16){ (_Float16)p0_.x, (_Float16)p0_.y, (_Float16)p1_.x, (_Float16)p1_.y, \
                  (_Float16)p2_.x, (_Float16)p2_.y, (_Float16)p3_.x, (_Float16)p3_.y, \
                  (_Float16)p4_.x, (_Float16)p4_.y, (_Float16)p5_.x, (_Float16)p5_.y, \
                  (_Float16)p6_.x, (_Float16)p6_.y, (_Float16)p7_.x, (_Float16)p7_.y }; \
} while (0)

#define LOAD_ROW(K, GATE, IDX) do {                                           \
  const float* sr_ = W_hh + ((size_t)(GATE) * HDIM + (i0 + (IDX))) * HDIM;    \
  LOAD_CHUNK(w##K##_0, sr_, 0); LOAD_CHUNK(w##K##_1, sr_, 1);                 \
  LOAD_CHUNK(w##K##_2, sr_, 2); LOAD_CHUNK(w##K##_3, sr_, 3);                 \
} while (0)

#define PAIR(V, J) (__builtin_shufflevector((V), (V), 2 * (J), 2 * (J) + 1))

#define DOT8(K, C)                                                            \
  a##K = dot2f(PAIR(w##K##_##C, 0), hp0, a##K);                               \
  a##K = dot2f(PAIR(w##K##_##C, 1), hp1, a##K);                               \
  a##K = dot2f(PAIR(w##K##_##C, 2), hp2, a##K);                               \
  a##K = dot2f(PAIR(w##K##_##C, 3), hp3, a##K);                               \
  a##K = dot2f(PAIR(w##K##_##C, 4), hp4, a##K);                               \
  a##K = dot2f(PAIR(w##K##_##C, 5), hp5, a##K);                               \
  a##K = dot2f(PAIR(w##K##_##C, 6), hp6, a##K);                               \
  a##K = dot2f(PAIR(w##K##_##C, 7), hp7, a##K);

#define CHUNK_STEP(C) {                                                       \
  UF u0_, u1_, u2_, u3_, u4_, u5_, u6_, u7_;                                  \
  u0_.u = h_lds[lane + 64 * ((C) * 8 + 0)];                                   \
  u1_.u = h_lds[lane + 64 * ((C) * 8 + 1)];                                   \
  u2_.u = h_lds[lane + 64 * ((C) * 8 + 2)];                                   \
  u3_.u = h_lds[lane + 64 * ((C) * 8 + 3)];                                   \
  u4_.u = h_lds[lane + 64 * ((C) * 8 + 4)];                                   \
  u5_.u = h_lds[lane + 64 * ((C) * 8 + 5)];                                   \
  u6_.u = h_lds[lane + 64 * ((C) * 8 + 6)];                                   \
  u7_.u = h_lds[lane + 64 * ((C) * 8 + 7)];                                   \
  f16x2 hp0 = u0_.h, hp1 = u1_.h, hp2 = u2_.h, hp3 = u3_.h;                   \
  f16x2 hp4 = u4_.h, hp5 = u5_.h, hp6 = u6_.h, hp7 = u7_.h;                   \
  DOT8(0, C) DOT8(1, C) DOT8(2, C) DOT8(3, C) DOT8(4, C) DOT8(5, C)          \
}

#define GX_INIT(K, GATE, IDX) {                                               \
  const int row_ = (GATE) * HDIM + (i0 + (IDX));                              \
  const float* s_ = W_ih + (size_t)row_ * 400;                                \
  float acc_ = 0.0f;                                                          \
  for (int c = lane; c < 400; c += 64) acc_ += s_[c] * x_lds[c];              \
  _Pragma("unroll")                                                           \
  for (int o = 32; o; o >>= 1) acc_ += __shfl_xor(acc_, o, 64);               \
  acc_ += b_ih[row_];                                                         \
  if ((GATE) != 2) acc_ += b_hh[row_];                                        \
  gx##K = acc_;                                                               \
}

// Software-pipelined tagged spin: one poll round always in flight. Checking
// set A waits only on A's vmcnt slots while set B is still outstanding, so
// the effective detection period is ~1 memory RTT instead of ~2. Lanes that
// match break and are exec-masked out (lane-sticky). Constant sleep(1).
#define SPIN_PIPE(RD, EXP, OUT0, OUT1, OUT2, OUT3) do {                       \
  u64 a0_ = ld64((RD) + p0), a1_ = ld64((RD) + p1),                           \
      a2_ = ld64((RD) + p2), a3_ = ld64((RD) + p3);                           \
  for (;;) {                                                                  \
    u64 b0_ = ld64((RD) + p0), b1_ = ld64((RD) + p1),                         \
        b2_ = ld64((RD) + p2), b3_ = ld64((RD) + p3);                         \
    if ((unsigned)(a0_ >> 32) == (EXP) && (unsigned)(a1_ >> 32) == (EXP) &&   \
        (unsigned)(a2_ >> 32) == (EXP) && (unsigned)(a3_ >> 32) == (EXP)) {   \
      OUT0 = a0_; OUT1 = a1_; OUT2 = a2_; OUT3 = a3_; break;                  \
    }                                                                         \
    __builtin_amdgcn_s_sleep(1);                                              \
    a0_ = ld64((RD) + p0); a1_ = ld64((RD) + p1);                             \
    a2_ = ld64((RD) + p2); a3_ = ld64((RD) + p3);                             \
    if ((unsigned)(b0_ >> 32) == (EXP) && (unsigned)(b1_ >> 32) == (EXP) &&   \
        (unsigned)(b2_ >> 32) == (EXP) && (unsigned)(b3_ >> 32) == (EXP)) {   \
      OUT0 = b0_; OUT1 = b1_; OUT2 = b2_; OUT3 = b3_; break;                  \
    }                                                                         \
    __builtin_amdgcn_s_sleep(1);                                              \
  }                                                                           \
} while (0)

// 256 blocks x 512 threads, persistent. Wave g owns h indices {2g, 2g+1}.
// Weights live in 24 named f16x16 SSA values (AGPR/VGPR file) — never LDS.
__global__ __attribute__((amdgpu_flat_work_group_size(NTHREADS, NTHREADS),
                          amdgpu_waves_per_eu(2, 2)))
void gru_persistent(const float* __restrict__ start,
                    const float* __restrict__ enc_h,
                    const float* __restrict__ W_ih,
                    const float* __restrict__ W_hh,
                    const float* __restrict__ b_ih,
                    const float* __restrict__ b_hh,
                    const float* __restrict__ W_out,
                    const float* __restrict__ b_out,
                    float* __restrict__ out,
                    u64* __restrict__ ws,
                    int T)
{
  __shared__ unsigned h_lds[NPAIR];          // h_t as f16x2 pairs
  __shared__ unsigned wout_lds[2][NPAIR];    // this block's W_out rows, f16x2
  __shared__ float    x_lds[400];            // relu(start)

  const int tid  = threadIdx.x;
  const int b    = blockIdx.x;
  const int wave = tid >> 6;
  const int lane = tid & 63;
  const int g    = b * WPB + wave;           // global wave id, 0..2047
  const int i0   = 2 * g;

  u64* buf0 = ws;            // [NPAIR] tagged h pairs, even steps
  u64* buf1 = ws + NPAIR;    // [NPAIR] odd steps
  // tag for h_t is (t+1).

  // ---- replay hardening: zero OWN slots before publishing anything.
  // Kills cross-replay stale-tag aliasing (replay N-1's final tags 2048/2049
  // would otherwise satisfy replay N's last-step/final-flush spins early).
  // Same-address store ordering guarantees consumers see 0 or fresh tags.
  if (lane == 0) {
    st64(&buf0[g], 0);
    st64(&buf1[g], 0);
  }

  // ---- stage x = relu(start) and this block's W_out rows (f16) into LDS ----
  if (tid < 400) x_lds[tid] = fmaxf(start[tid], 0.0f);
  for (int s = 0; s < 2; ++s) {
    int row = 2 * b + s;
    if (row < 401) {
      for (int p = tid; p < NPAIR; p += NTHREADS) {
        float2 wv = *(const float2*)(W_out + (size_t)row * HDIM + 2 * p);
        UF u; u.h = (f16x2){(_Float16)wv.x, (_Float16)wv.y};
        wout_lds[s][p] = u.u;
      }
    }
  }
  __syncthreads();

  // ---- persistent W_hh fragment: 6 rows x 4 chunks of f16x16 ----
  f16x16 w0_0, w0_1, w0_2, w0_3;
  f16x16 w1_0, w1_1, w1_2, w1_3;
  f16x16 w2_0, w2_1, w2_2, w2_3;
  f16x16 w3_0, w3_1, w3_2, w3_3;
  f16x16 w4_0, w4_1, w4_2, w4_3;
  f16x16 w5_0, w5_1, w5_2, w5_3;
  LOAD_ROW(0, 0, 0); LOAD_ROW(1, 0, 1);   // r gate
  LOAD_ROW(2, 1, 0); LOAD_ROW(3, 1, 1);   // z gate
  LOAD_ROW(4, 2, 0); LOAD_ROW(5, 2, 1);   // n gate

  // ---- gx = W_ih @ relu(start) + b_ih (+ b_hh folded for r,z) ----
  float gx0, gx1, gx2, gx3, gx4, gx5;
  GX_INIT(0, 0, 0); GX_INIT(1, 0, 1);
  GX_INIT(2, 1, 0); GX_INIT(3, 1, 1);
  GX_INIT(4, 2, 0); GX_INIT(5, 2, 1);
  const float bhn0 = b_hh[2 * HDIM + i0];
  const float bhn1 = b_hh[2 * HDIM + i0 + 1];

  // ---- h carry (fp32, owner registers) ----
  float h0 = enc_h[i0], h1 = enc_h[i0 + 1];

  // publish h_0 (tag 1)
  if (lane == 0) {
    UF u; u.h = (f16x2){(_Float16)h0, (_Float16)h1};
    st64(&buf0[g], ((u64)1 << 32) | (u64)u.u);
  }

  // ---- main scan ----
  for (int t = 0; t < T; ++t) {
    u64* rd = (t & 1) ? buf1 : buf0;   // holds h_t, tag t+1
    u64* wr = (t & 1) ? buf0 : buf1;   // gets h_{t+1}, tag t+2
    const unsigned exp = (unsigned)(t + 1);

    // phase 1: pipelined tagged spin + broadcast -> LDS (this IS the grid barrier)
    {
      const int p0 = tid, p1 = tid + NTHREADS, p2 = tid + 2 * NTHREADS, p3 = tid + 3 * NTHREADS;
      u64 v0, v1, v2, v3;
      SPIN_PIPE(rd, exp, v0, v1, v2, v3);
      h_lds[p0] = (unsigned)v0; h_lds[p1] = (unsigned)v1;
      h_lds[p2] = (unsigned)v2; h_lds[p3] = (unsigned)v3;
    }
    __syncthreads();

    // gh = W_hh @ h_t : 6 rows per wave
    float a0 = 0.f, a1 = 0.f, a2 = 0.f, a3 = 0.f, a4 = 0.f, a5 = 0.f;
    CHUNK_STEP(0); CHUNK_STEP(1); CHUNK_STEP(2); CHUNK_STEP(3);
    #pragma unroll
    for (int off = 32; off; off >>= 1) {
      a0 += __shfl_xor(a0, off, 64);
      a1 += __shfl_xor(a1, off, 64);
      a2 += __shfl_xor(a2, off, 64);
      a3 += __shfl_xor(a3, off, 64);
      a4 += __shfl_xor(a4, off, 64);
      a5 += __shfl_xor(a5, off, 64);
    }

    float r0 = sigmoidf_(gx0 + a0);
    float r1 = sigmoidf_(gx1 + a1);
    float z0 = sigmoidf_(gx2 + a2);
    float z1 = sigmoidf_(gx3 + a3);
    float n0 = tanhf_(gx4 + r0 * (a4 + bhn0));
    float n1 = tanhf_(gx5 + r1 * (a5 + bhn1));
    h0 = (1.0f - z0) * n0 + z0 * h0;
    h1 = (1.0f - z1) * n1 + z1 * h1;

    // publish h_{t+1} ASAP (tag t+2)
    if (lane == 0) {
      UF u; u.h = (f16x2){(_Float16)h0, (_Float16)h1};
      st64(&wr[g], ((u64)(unsigned)(t + 2) << 32) | (u64)u.u);
    }

    // output for step t-1 (uses h_t, still in LDS) — hides in others' spin
    if (t > 0 && wave < 2) {
      int row = 2 * b + wave;
      if (row < 401) {
        float acc = 0.0f;
        #pragma unroll
        for (int j = 0; j < 32; ++j) {
          int p = lane + 64 * j;
          UF a, hh; a.u = wout_lds[wave][p]; hh.u = h_lds[p];
          acc = dot2f(a.h, hh.h, acc);
        }
        #pragma unroll
        for (int off = 32; off; off >>= 1) acc += __shfl_xor(acc, off, 64);
        if (lane == 0) {
          acc += b_out[row];
          if (row < 400) out[(size_t)(t - 1) * 400 + row] = tanhf_(acc);
          else           out[(size_t)400 * T + (t - 1)]   = sigmoidf_(acc);
        }
      }
    }
    __syncthreads();   // protect h_lds before next phase-1 overwrite
  }

  // ---- final output flush: o_{T-1} = W_out @ h_T (tag T+1) ----
  {
    u64* rd = (T & 1) ? buf1 : buf0;
    const unsigned exp = (unsigned)(T + 1);
    const int p0 = tid, p1 = tid + NTHREADS, p2 = tid + 2 * NTHREADS, p3 = tid + 3 * NTHREADS;
    u64 v0, v1, v2, v3;
    SPIN_PIPE(rd, exp, v0, v1, v2, v3);
    h_lds[p0] = (unsigned)v0; h_lds[p1] = (unsigned)v1;
    h_lds[p2] = (unsigned)v2; h_lds[p3] = (unsigned)v3;
    __syncthreads();
    if (wave < 2) {
      int row = 2 * b + wave;
      if (row < 401) {
        float acc = 0.0f;
        #pragma unroll
        for (int j = 0; j < 32; ++j) {
          int p = lane + 64 * j;
          UF a, hh; a.u = wout_lds[wave][p]; hh.u = h_lds[p];
          acc = dot2f(a.h, hh.h, acc);
        }
        #pragma unroll
        for (int off = 32; off; off >>= 1) acc += __shfl_xor(acc, off, 64);
        if (lane == 0) {
          acc += b_out[row];
          if (row < 400) out[(size_t)(T - 1) * 400 + row] = tanhf_(acc);
          else           out[(size_t)400 * T + (T - 1)]   = sigmoidf_(acc);
        }
      }
    }
  }
}

extern "C" void kernel_launch(void* const* d_in, const int* in_sizes, int n_in,
                              void* d_out, int out_size, void* d_ws, size_t ws_size,
                              hipStream_t stream) {
  (void)in_sizes; (void)n_in; (void)ws_size;
  const float* start = (const float*)d_in[0];
  const float* enc_h = (const float*)d_in[1];
  const float* W_ih  = (const float*)d_in[2];
  const float* W_hh  = (const float*)d_in[3];
  const float* b_ih  = (const float*)d_in[4];
  const float* b_hh  = (const float*)d_in[5];
  const float* W_out = (const float*)d_in[6];
  const float* b_out = (const float*)d_in[7];
  float* out = (float*)d_out;
  u64* ws = (u64*)d_ws;

  int T = out_size / 401;   // outputs T*400 + stops T

  gru_persistent<<<NBLOCKS, NTHREADS, 0, stream>>>(
      start, enc_h, W_ih, W_hh, b_ih, b_hh, W_out, b_out, out, ws, T);
}

// Round 5
// 8964.445 us; speedup vs baseline: 1.6969x; 1.6969x over previous
//
#include <hip/hip_runtime.h>
#include <math.h>

#define NBLOCKS 256
#define NTHREADS 512
#define WPB 8                 // waves per block
#define HDIM 4096
#define NPAIR (HDIM/2)        // 2048 f16x2 pairs

typedef _Float16 f16x2  __attribute__((ext_vector_type(2)));
typedef _Float16 f16x16 __attribute__((ext_vector_type(16)));
typedef unsigned u32x4 __attribute__((ext_vector_type(4)));
typedef unsigned long long u64;

union UF { unsigned u; f16x2 h; };

__device__ __forceinline__ float dot2f(f16x2 a, f16x2 b, float c) {
  return __builtin_amdgcn_fdot2(a, b, c, false);   // v_dot2_f32_f16
}
__device__ __forceinline__ float sigmoidf_(float x) {
  return 1.0f / (1.0f + __expf(-x));
}
__device__ __forceinline__ float tanhf_(float x) {
  float a = fabsf(x);
  float t = __expf(-2.0f * a);
  float r = (1.0f - t) / (1.0f + t);
  return copysignf(r, x);
}
__device__ __forceinline__ void st64(u64* p, u64 v) {
  __hip_atomic_store(p, v, __ATOMIC_RELAXED, __HIP_MEMORY_SCOPE_AGENT);
}
__device__ __forceinline__ void st64_rel(u64* p, u64 v) {
  __hip_atomic_store(p, v, __ATOMIC_RELEASE, __HIP_MEMORY_SCOPE_AGENT);
}

// ---- load one f16x16 chunk (8 f16x2 pairs, pair j at (const float2*)SRC + lane + 64*j) ----
#define LOAD_CHUNK(VAR, SRC, C) do {                                          \
  const float2* s_ = (const float2*)(SRC) + lane + 64 * ((C) * 8);            \
  float2 p0_ = s_[0];   float2 p1_ = s_[64];  float2 p2_ = s_[128];           \
  float2 p3_ = s_[192]; float2 p4_ = s_[256]; float2 p5_ = s_[320];           \
  float2 p6_ = s_[384]; float2 p7_ = s_[448];                                 \
  VAR = (f16x16){ (_Float16)p0_.x, (_Float16)p0_.y, (_Float16)p1_.x, (_Float16)p1_.y, \
                  (_Float16)p2_.x, (_Float16)p2_.y, (_Float16)p3_.x, (_Float16)p3_.y, \
                  (_Float16)p4_.x, (_Float16)p4_.y, (_Float16)p5_.x, (_Float16)p5_.y, \
                  (_Float16)p6_.x, (_Float16)p6_.y, (_Float16)p7_.x, (_Float16)p7_.y }; \
} while (0)

#define LOAD_ROW(K, GATE, IDX) do {                                           \
  const float* sr_ = W_hh + ((size_t)(GATE) * HDIM + (i0 + (IDX))) * HDIM;    \
  LOAD_CHUNK(w##K##_0, sr_, 0); LOAD_CHUNK(w##K##_1, sr_, 1);                 \
  LOAD_CHUNK(w##K##_2, sr_, 2); LOAD_CHUNK(w##K##_3, sr_, 3);                 \
} while (0)

#define PAIR(V, J) (__builtin_shufflevector((V), (V), 2 * (J), 2 * (J) + 1))

#define DOT8(K, C)                                                            \
  a##K = dot2f(PAIR(w##K##_##C, 0), hp0, a##K);                               \
  a##K = dot2f(PAIR(w##K##_##C, 1), hp1, a##K);                               \
  a##K = dot2f(PAIR(w##K##_##C, 2), hp2, a##K);                               \
  a##K = dot2f(PAIR(w##K##_##C, 3), hp3, a##K);                               \
  a##K = dot2f(PAIR(w##K##_##C, 4), hp4, a##K);                               \
  a##K = dot2f(PAIR(w##K##_##C, 5), hp5, a##K);                               \
  a##K = dot2f(PAIR(w##K##_##C, 6), hp6, a##K);                               \
  a##K = dot2f(PAIR(w##K##_##C, 7), hp7, a##K);

#define CHUNK_STEP(C) {                                                       \
  UF u0_, u1_, u2_, u3_, u4_, u5_, u6_, u7_;                                  \
  u0_.u = h_lds[lane + 64 * ((C) * 8 + 0)];                                   \
  u1_.u = h_lds[lane + 64 * ((C) * 8 + 1)];                                   \
  u2_.u = h_lds[lane + 64 * ((C) * 8 + 2)];                                   \
  u3_.u = h_lds[lane + 64 * ((C) * 8 + 3)];                                   \
  u4_.u = h_lds[lane + 64 * ((C) * 8 + 4)];                                   \
  u5_.u = h_lds[lane + 64 * ((C) * 8 + 5)];                                   \
  u6_.u = h_lds[lane + 64 * ((C) * 8 + 6)];                                   \
  u7_.u = h_lds[lane + 64 * ((C) * 8 + 7)];                                   \
  f16x2 hp0 = u0_.h, hp1 = u1_.h, hp2 = u2_.h, hp3 = u3_.h;                   \
  f16x2 hp4 = u4_.h, hp5 = u5_.h, hp6 = u6_.h, hp7 = u7_.h;                   \
  DOT8(0, C) DOT8(1, C) DOT8(2, C) DOT8(3, C) DOT8(4, C) DOT8(5, C)          \
}

#define GX_INIT(K, GATE, IDX) {                                               \
  const int row_ = (GATE) * HDIM + (i0 + (IDX));                              \
  const float* s_ = W_ih + (size_t)row_ * 400;                                \
  float acc_ = 0.0f;                                                          \
  for (int c = lane; c < 400; c += 64) acc_ += s_[c] * x_lds[c];              \
  _Pragma("unroll")                                                           \
  for (int o = 32; o; o >>= 1) acc_ += __shfl_xor(acc_, o, 64);               \
  acc_ += b_ih[row_];                                                         \
  if ((GATE) != 2) acc_ += b_hh[row_];                                        \
  gx##K = acc_;                                                               \
}

// Tagged spin with 16B coherent loads: thread covers slots {2t,2t+1} and
// {1024+2t,1024+2t+1} via two global_load_dwordx4 sc0 sc1 (device-coherent,
// cache-bypassing). Half the MALL request count of the 4x8B version, same
// bytes, same loop shape (single batch -> check -> sleep(1)), same per-lane
// exec-mask break. Tearing across the two slots in one 16B load is benign:
// both tags are checked, each 8B slot is written atomically by its producer.
#define SPIN16(RD, EXP, A, B) do {                                            \
  const u64* ap_ = (RD) + 2 * tid;                                            \
  const u64* bp_ = (RD) + 1024 + 2 * tid;                                     \
  for (;;) {                                                                  \
    asm volatile(                                                             \
      "global_load_dwordx4 %0, %2, off sc0 sc1\n\t"                           \
      "global_load_dwordx4 %1, %3, off sc0 sc1\n\t"                           \
      "s_waitcnt vmcnt(0)"                                                    \
      : "=&v"(A), "=&v"(B) : "v"(ap_), "v"(bp_) : "memory");                  \
    if (A.s1 == (EXP) && A.s3 == (EXP) && B.s1 == (EXP) && B.s3 == (EXP))     \
      break;                                                                  \
    __builtin_amdgcn_s_sleep(1);                                              \
  }                                                                           \
} while (0)

// 256 blocks x 512 threads, persistent. Wave g owns h indices {2g, 2g+1}.
// Weights live in 24 named f16x16 SSA values (AGPR/VGPR file) — never LDS
// (R3: LDS weights cost ds_read latency on the critical path, -13%).
__global__ __attribute__((amdgpu_flat_work_group_size(NTHREADS, NTHREADS),
                          amdgpu_waves_per_eu(2, 2)))
void gru_persistent(const float* __restrict__ start,
                    const float* __restrict__ enc_h,
                    const float* __restrict__ W_ih,
                    const float* __restrict__ W_hh,
                    const float* __restrict__ b_ih,
                    const float* __restrict__ b_hh,
                    const float* __restrict__ W_out,
                    const float* __restrict__ b_out,
                    float* __restrict__ out,
                    u64* __restrict__ ws,
                    int T)
{
  __shared__ unsigned h_lds[NPAIR];          // h_t as f16x2 pairs
  __shared__ unsigned wout_lds[2][NPAIR];    // this block's W_out rows, f16x2
  __shared__ float    x_lds[400];            // relu(start)

  const int tid  = threadIdx.x;
  const int b    = blockIdx.x;
  const int wave = tid >> 6;
  const int lane = tid & 63;
  const int g    = b * WPB + wave;           // global wave id, 0..2047
  const int i0   = 2 * g;

  u64* buf0 = ws;            // [NPAIR] tagged h pairs, even steps
  u64* buf1 = ws + NPAIR;    // [NPAIR] odd steps
  // tag for h_t is (t+1).

  // ---- replay hardening (validated in R4): zero OWN slots before any
  // publish. Kills cross-replay stale-tag aliasing (prev replay's final
  // tags 2048 in buf1 would satisfy this replay's t=2047 spin early).
  if (lane == 0) {
    st64(&buf0[g], 0);
    st64(&buf1[g], 0);
  }

  // ---- stage x = relu(start) and this block's W_out rows (f16) into LDS ----
  if (tid < 400) x_lds[tid] = fmaxf(start[tid], 0.0f);
  for (int s = 0; s < 2; ++s) {
    int row = 2 * b + s;
    if (row < 401) {
      for (int p = tid; p < NPAIR; p += NTHREADS) {
        float2 wv = *(const float2*)(W_out + (size_t)row * HDIM + 2 * p);
        UF u; u.h = (f16x2){(_Float16)wv.x, (_Float16)wv.y};
        wout_lds[s][p] = u.u;
      }
    }
  }
  __syncthreads();

  // ---- persistent W_hh fragment: 6 rows x 4 chunks of f16x16 ----
  f16x16 w0_0, w0_1, w0_2, w0_3;
  f16x16 w1_0, w1_1, w1_2, w1_3;
  f16x16 w2_0, w2_1, w2_2, w2_3;
  f16x16 w3_0, w3_1, w3_2, w3_3;
  f16x16 w4_0, w4_1, w4_2, w4_3;
  f16x16 w5_0, w5_1, w5_2, w5_3;
  LOAD_ROW(0, 0, 0); LOAD_ROW(1, 0, 1);   // r gate
  LOAD_ROW(2, 1, 0); LOAD_ROW(3, 1, 1);   // z gate
  LOAD_ROW(4, 2, 0); LOAD_ROW(5, 2, 1);   // n gate

  // ---- gx = W_ih @ relu(start) + b_ih (+ b_hh folded for r,z) ----
  float gx0, gx1, gx2, gx3, gx4, gx5;
  GX_INIT(0, 0, 0); GX_INIT(1, 0, 1);
  GX_INIT(2, 1, 0); GX_INIT(3, 1, 1);
  GX_INIT(4, 2, 0); GX_INIT(5, 2, 1);
  const float bhn0 = b_hh[2 * HDIM + i0];
  const float bhn1 = b_hh[2 * HDIM + i0 + 1];

  // ---- h carry (fp32, owner registers) ----
  float h0 = enc_h[i0], h1 = enc_h[i0 + 1];

  // publish h_0 (tag 1) — RELEASE so the zeroing above is globally visible
  // before any consumer can observe a valid tag from this wave.
  if (lane == 0) {
    UF u; u.h = (f16x2){(_Float16)h0, (_Float16)h1};
    st64_rel(&buf0[g], ((u64)1 << 32) | (u64)u.u);
  }

  // ---- main scan ----
  for (int t = 0; t < T; ++t) {
    u64* rd = (t & 1) ? buf1 : buf0;   // holds h_t, tag t+1
    u64* wr = (t & 1) ? buf0 : buf1;   // gets h_{t+1}, tag t+2
    const unsigned exp = (unsigned)(t + 1);

    // phase 1: tagged spin + broadcast -> LDS (this IS the grid barrier)
    {
      u32x4 A, B;
      SPIN16(rd, exp, A, B);
      *(uint2*)&h_lds[2 * tid]        = (uint2){A.s0, A.s2};
      *(uint2*)&h_lds[1024 + 2 * tid] = (uint2){B.s0, B.s2};
    }
    __syncthreads();

    // gh = W_hh @ h_t : 6 rows per wave
    float a0 = 0.f, a1 = 0.f, a2 = 0.f, a3 = 0.f, a4 = 0.f, a5 = 0.f;
    CHUNK_STEP(0); CHUNK_STEP(1); CHUNK_STEP(2); CHUNK_STEP(3);
    #pragma unroll
    for (int off = 32; off; off >>= 1) {
      a0 += __shfl_xor(a0, off, 64);
      a1 += __shfl_xor(a1, off, 64);
      a2 += __shfl_xor(a2, off, 64);
      a3 += __shfl_xor(a3, off, 64);
      a4 += __shfl_xor(a4, off, 64);
      a5 += __shfl_xor(a5, off, 64);
    }

    float r0 = sigmoidf_(gx0 + a0);
    float r1 = sigmoidf_(gx1 + a1);
    float z0 = sigmoidf_(gx2 + a2);
    float z1 = sigmoidf_(gx3 + a3);
    float n0 = tanhf_(gx4 + r0 * (a4 + bhn0));
    float n1 = tanhf_(gx5 + r1 * (a5 + bhn1));
    h0 = (1.0f - z0) * n0 + z0 * h0;
    h1 = (1.0f - z1) * n1 + z1 * h1;

    // publish h_{t+1} ASAP (tag t+2)
    if (lane == 0) {
      UF u; u.h = (f16x2){(_Float16)h0, (_Float16)h1};
      st64(&wr[g], ((u64)(unsigned)(t + 2) << 32) | (u64)u.u);
    }

    // output for step t-1 (uses h_t, still in LDS) — hides in others' spin
    if (t > 0 && wave < 2) {
      int row = 2 * b + wave;
      if (row < 401) {
        float acc = 0.0f;
        #pragma unroll
        for (int j = 0; j < 32; ++j) {
          int p = lane + 64 * j;
          UF a, hh; a.u = wout_lds[wave][p]; hh.u = h_lds[p];
          acc = dot2f(a.h, hh.h, acc);
        }
        #pragma unroll
        for (int off = 32; off; off >>= 1) acc += __shfl_xor(acc, off, 64);
        if (lane == 0) {
          acc += b_out[row];
          if (row < 400) out[(size_t)(t - 1) * 400 + row] = tanhf_(acc);
          else           out[(size_t)400 * T + (t - 1)]   = sigmoidf_(acc);
        }
      }
    }
    __syncthreads();   // protect h_lds before next phase-1 overwrite
  }

  // ---- final output flush: o_{T-1} = W_out @ h_T (tag T+1) ----
  {
    u64* rd = (T & 1) ? buf1 : buf0;
    const unsigned exp = (unsigned)(T + 1);
    u32x4 A, B;
    SPIN16(rd, exp, A, B);
    *(uint2*)&h_lds[2 * tid]        = (uint2){A.s0, A.s2};
    *(uint2*)&h_lds[1024 + 2 * tid] = (uint2){B.s0, B.s2};
    __syncthreads();
    if (wave < 2) {
      int row = 2 * b + wave;
      if (row < 401) {
        float acc = 0.0f;
        #pragma unroll
        for (int j = 0; j < 32; ++j) {
          int p = lane + 64 * j;
          UF a, hh; a.u = wout_lds[wave][p]; hh.u = h_lds[p];
          acc = dot2f(a.h, hh.h, acc);
        }
        #pragma unroll
        for (int off = 32; off; off >>= 1) acc += __shfl_xor(acc, off, 64);
        if (lane == 0) {
          acc += b_out[row];
          if (row < 400) out[(size_t)(T - 1) * 400 + row] = tanhf_(acc);
          else           out[(size_t)400 * T + (T - 1)]   = sigmoidf_(acc);
        }
      }
    }
  }
}

extern "C" void kernel_launch(void* const* d_in, const int* in_sizes, int n_in,
                              void* d_out, int out_size, void* d_ws, size_t ws_size,
                              hipStream_t stream) {
  (void)in_sizes; (void)n_in; (void)ws_size;
  const float* start = (const float*)d_in[0];
  const float* enc_h = (const float*)d_in[1];
  const float* W_ih  = (const float*)d_in[2];
  const float* W_hh  = (const float*)d_in[3];
  const float* b_ih  = (const float*)d_in[4];
  const float* b_hh  = (const float*)d_in[5];
  const float* W_out = (const float*)d_in[6];
  const float* b_out = (const float*)d_in[7];
  float* out = (float*)d_out;
  u64* ws = (u64*)d_ws;

  int T = out_size / 401;   // outputs T*400 + stops T

  gru_persistent<<<NBLOCKS, NTHREADS, 0, stream>>>(
      start, enc_h, W_ih, W_hh, b_ih, b_hh, W_out, b_out, out, ws, T);
}